// Round 6
// baseline (260.310 us; speedup 1.0000x reference)
//
#include <hip/hip_runtime.h>

#define NNODES 50000
#define NEDGES 800000
#define CHUNK 3125          // edges per CSR block (256 blocks * 3125 = 800000)

typedef __attribute__((ext_vector_type(8))) short short8;
typedef __attribute__((ext_vector_type(4))) float floatx4;
typedef __attribute__((ext_vector_type(8))) _Float16 f16x8;

// async global->LDS, 16B per lane (global_load_lds_dwordx4).
// LDS dest MUST be wave-uniform base + lane*16.
__device__ __forceinline__ void async16(const void* g, void* l) {
    __builtin_amdgcn_global_load_lds(
        (const __attribute__((address_space(1))) unsigned int*)g,
        (__attribute__((address_space(3))) unsigned int*)l, 16, 0, 0);
}

__device__ __forceinline__ void split_bf16(float v, short& hi, short& lo) {
    unsigned u = __float_as_uint(v);
    unsigned hu = u & 0xffff0000u;
    hi = (short)(hu >> 16);
    float r = v - __uint_as_float(hu);
    lo = (short)(__float_as_uint(r) >> 16);
}

// ------ prep: weight transpose/split + coarse histogram + deg atomics ----

#define PREP_WBLK 224
#define PREP_TOT  (PREP_WBLK + 256)

__global__ __launch_bounds__(256) void k_prep(
    const float* __restrict__ W0, short* __restrict__ W0h, short* __restrict__ W0l,
    const float* __restrict__ W1, short* __restrict__ W1h, short* __restrict__ W1l,
    const float* __restrict__ W2, short* __restrict__ W2h, short* __restrict__ W2l,
    const int* __restrict__ dst, int* __restrict__ hist2d,
    int* __restrict__ deg) {
    int b = blockIdx.x, t = threadIdx.x;
    if (b < PREP_WBLK) {
        int id = b * 256 + t;
        const float* W; short *Wh, *Wl; int K, F;
        if (id < 32768) { W = W0; Wh = W0h; Wl = W0l; K = 256; F = 128; }
        else if (id < 49152) { id -= 32768; W = W1; Wh = W1h; Wl = W1l; K = 128; F = 128; }
        else if (id < 57344) { id -= 49152; W = W2; Wh = W2h; Wl = W2l; K = 128; F = 64; }
        else return;
        int f = id / K, k = id - f * K;
        short h, l;
        split_bf16(W[(size_t)k * F + f], h, l);
        Wh[id] = h;
        Wl[id] = l;
    } else {
        // per-block coarse histogram of dst>>8 + global fine degree
        __shared__ int h[256];
        int bb = b - PREP_WBLK;
        h[t] = 0;
        __syncthreads();
        int e0 = bb * CHUNK;
#pragma unroll
        for (int k = 0; k < 13; k++) {
            int o = k * 256 + t;
            if (o < CHUNK) {
                int d = dst[e0 + o];
                atomicAdd(&h[d >> 8], 1);
                atomicAdd(&deg[d], 1);        // fine degree (for gemm0's dinv)
            }
        }
        __syncthreads();
        hist2d[bb * 256 + t] = h[t];
    }
}

// ------ FUSED p2 (coarse scatter) || gemm0 (x @ W0) ----------------------
// R6: blocks [0,256) = exact R0 p2; blocks [256,256+MB) = exact R0 gemm0
// with dinv computed on the fly from deg (identical value: rsqrt(deg+1)).
// p2's 256 low-occupancy scan/scatter blocks hide under gemm0's work.

#define G0_MB ((NNODES + 63) / 64)     // 782

__global__ __launch_bounds__(256) void k_p2g0(
    const int* __restrict__ src, const int* __restrict__ dst,
    const int* __restrict__ hist2d, unsigned* __restrict__ buck,
    const float* __restrict__ x, const short* __restrict__ Bh,
    const short* __restrict__ Bl, const int* __restrict__ deg,
    _Float16* __restrict__ g16) {
    __shared__ __align__(16) short sAh[64 * 64], sAl[64 * 64];
    __shared__ __align__(16) short sBh[128 * 64], sBl[128 * 64];
    __shared__ int ex[256], cur[256];

    if (blockIdx.x < 256) {
        // ---------------- p2 role ----------------
        int t = threadIdx.x, b = blockIdx.x;
        int tot = 0, pre = 0;
        for (int bb = 0; bb < 256; bb++) {
            int v = hist2d[bb * 256 + t];
            tot += v;
            pre += (bb < b) ? v : 0;
        }
        ex[t] = tot;
        __syncthreads();
        for (int o = 1; o < 256; o <<= 1) {
            int xx = (t >= o) ? ex[t - o] : 0;
            __syncthreads();
            ex[t] += xx;
            __syncthreads();
        }
        cur[t] = (ex[t] - tot) + pre;
        __syncthreads();
        int e0 = b * CHUNK;
#pragma unroll
        for (int k = 0; k < 13; k++) {
            int o = k * 256 + t;
            if (o < CHUNK) {
                int s = src[e0 + o], d = dst[e0 + o];
                int p = atomicAdd(&cur[d >> 8], 1);   // LDS atomic only
                buck[p] = (unsigned)s | ((unsigned)(d & 255) << 16);
            }
        }
        return;
    }

    // ---------------- gemm0 role ----------------
    const int t = threadIdx.x, lane = t & 63, w = t >> 6;
    const int row0 = (blockIdx.x - 256) * 64;
    const int lr = lane >> 3, lz = lane & 7;
    const int swz = (lz ^ lr) * 8;
    const int fr = lane & 15, fq = lane >> 4;
    floatx4 acc[8] = {};
    const int ar = t >> 2, ac = t & 3;
    int garow = row0 + ar;
    if (garow >= NNODES) garow = NNODES - 1;
    const float* xrow = x + (size_t)garow * 256 + ac * 16;

    for (int k0 = 0; k0 < 256; k0 += 64) {
        const float4* xp = (const float4*)(xrow + k0);
        float4 f0 = xp[0], f1 = xp[1], f2 = xp[2], f3 = xp[3];
        float va[16] = {f0.x, f0.y, f0.z, f0.w, f1.x, f1.y, f1.z, f1.w,
                        f2.x, f2.y, f2.z, f2.w, f3.x, f3.y, f3.z, f3.w};
        short8 h0, h1, l0, l1;
#pragma unroll
        for (int j = 0; j < 8; j++) {
            short h, l;
            split_bf16(va[j], h, l);     h0[j] = h; l0[j] = l;
            split_bf16(va[8 + j], h, l); h1[j] = h; l1[j] = l;
        }
        int c0 = ac * 2;
        *(short8*)&sAh[ar * 64 + ((c0 ^ (ar & 7)) * 8)] = h0;
        *(short8*)&sAh[ar * 64 + (((c0 + 1) ^ (ar & 7)) * 8)] = h1;
        *(short8*)&sAl[ar * 64 + ((c0 ^ (ar & 7)) * 8)] = l0;
        *(short8*)&sAl[ar * 64 + (((c0 + 1) ^ (ar & 7)) * 8)] = l1;
#pragma unroll
        for (int jj = 0; jj < 4; jj++) {
            int j = w * 4 + jj;
            size_t go = (size_t)(j * 8 + lr) * 256 + k0 + swz;
            async16(&Bh[go], &sBh[j * 512 + lane * 8]);
            async16(&Bl[go], &sBl[j * 512 + lane * 8]);
        }
        __syncthreads();
#pragma unroll
        for (int ks = 0; ks < 2; ks++) {
            int R = w * 16 + fr;
            int ca = ((ks * 4 + fq) ^ (R & 7)) * 8;
            short8 ah = *(const short8*)&sAh[R * 64 + ca];
            short8 al = *(const short8*)&sAl[R * 64 + ca];
#pragma unroll
            for (int nt = 0; nt < 8; nt++) {
                int n = nt * 16 + fr;
                int cb = ((ks * 4 + fq) ^ (n & 7)) * 8;
                short8 bh = *(const short8*)&sBh[n * 64 + cb];
                short8 bl = *(const short8*)&sBl[n * 64 + cb];
                acc[nt] = __builtin_amdgcn_mfma_f32_16x16x32_bf16(ah, bh, acc[nt], 0, 0, 0);
                acc[nt] = __builtin_amdgcn_mfma_f32_16x16x32_bf16(ah, bl, acc[nt], 0, 0, 0);
                acc[nt] = __builtin_amdgcn_mfma_f32_16x16x32_bf16(al, bh, acc[nt], 0, 0, 0);
            }
        }
        __syncthreads();
    }
#pragma unroll
    for (int rr = 0; rr < 4; rr++) {
        int gw = row0 + w * 16 + fq * 4 + rr;
        if (gw < NNODES) {
            float dv = rsqrtf((float)deg[gw] + 1.0f);   // == p3's dinv
#pragma unroll
            for (int nt = 0; nt < 8; nt++)
                g16[(size_t)gw * 128 + nt * 16 + fr] =
                    (_Float16)(acc[nt][rr] * dv);
        }
    }
}

// P3 (self-scanning, R0): finalize coarse bin b -> rowptr/dinv/ssrc.
__global__ __launch_bounds__(256) void k_p3(const unsigned* __restrict__ buck,
                                            const int* __restrict__ hist2d,
                                            int* __restrict__ rowptr,
                                            float* __restrict__ dinv,
                                            int* __restrict__ ssrc) {
    __shared__ int ex[256], cur[256], h[256], sS0[1], sS[1];
    int t = threadIdx.x, b = blockIdx.x;
    int tot = 0;
    for (int bb = 0; bb < 256; bb++) tot += hist2d[bb * 256 + t];
    ex[t] = tot;
    __syncthreads();
    for (int o = 1; o < 256; o <<= 1) {
        int xx = (t >= o) ? ex[t - o] : 0;
        __syncthreads();
        ex[t] += xx;
        __syncthreads();
    }
    if (t == b) { sS0[0] = ex[t] - tot; sS[0] = tot; }
    h[t] = 0;
    __syncthreads();
    int s0 = sS0[0], S = sS[0];
    for (int i = t; i < S; i += 256)
        atomicAdd(&h[(buck[s0 + i] >> 16) & 255], 1);
    __syncthreads();
    int v = h[t];
    ex[t] = v;
    __syncthreads();
    for (int o = 1; o < 256; o <<= 1) {
        int xx = (t >= o) ? ex[t - o] : 0;
        __syncthreads();
        ex[t] += xx;
        __syncthreads();
    }
    int excl = ex[t] - v;
    int n = b * 256 + t;
    if (n < NNODES) {
        rowptr[n] = s0 + excl;
        dinv[n] = rsqrtf((float)v + 1.0f);
    }
    if (b == 0 && t == 0) rowptr[NNODES] = NEDGES;
    cur[t] = excl;
    __syncthreads();
    for (int i = t; i < S; i += 256) {
        unsigned pk = buck[s0 + i];
        int dl = (pk >> 16) & 255;
        int p = atomicAdd(&cur[dl], 1);
        ssrc[s0 + p] = (int)(pk & 0xFFFFu);
    }
}

// ------ FUSED agg(layer L) + gemm(layer L+1) (R5, proven) ----------------
// Phase A: single pass, 8 threads/row x 32 rows, 2 chunks/thread ->
// 8 gather loads in flight with the 4-edge unroll. LDS 32KB.

template <int BN>
__global__ __launch_bounds__(256) void k_fagg(
    const _Float16* __restrict__ gin,
    const int* __restrict__ ssrc,
    const int* __restrict__ rowptr,
    const float* __restrict__ dinv,
    const float* __restrict__ bias,
    const short* __restrict__ Bh, const short* __restrict__ Bl,
    _Float16* __restrict__ gout) {
    constexpr int BM = 32;
    constexpr int NT = BN / 32;          // col tiles per wave (4 or 2)
    __shared__ __align__(16) short sAh[2 * BM * 64], sAl[2 * BM * 64]; // 8+8 KB
    __shared__ __align__(16) char uB[16384];                          // 16 KB union

    const int t = threadIdx.x, lane = t & 63, w = t >> 6;
    const int row0 = blockIdx.x * BM;

    // ---- phase A: aggregate (single pass; sED aliases uB) ----
    int (*sED)[64] = (int(*)[64])uB;    // 32 x 64 ints = 8KB
    const int ln = t >> 3;      // row (0..31)
    const int c8 = t & 7;       // chunk pair: handles c8 and c8+8
    const f16x8* gp = (const f16x8*)gin;

    int gr = row0 + ln;
    if (gr >= NNODES) gr = NNODES - 1;
    int e0 = rowptr[gr], e1 = rowptr[gr + 1];
    int deg = e1 - e0;
    int cnt = deg < 64 ? deg : 64;
    for (int i = c8; i < cnt; i += 8) sED[ln][i] = ssrc[e0 + i];
    __syncthreads();

    f16x8 svA = gp[(size_t)gr * 16 + c8];          // self term
    f16x8 svB = gp[(size_t)gr * 16 + c8 + 8];
    float aA0[8], aA1[8], aB0[8], aB1[8];
#pragma unroll
    for (int j = 0; j < 8; j++) {
        aA0[j] = (float)svA[j]; aA1[j] = 0.f;
        aB0[j] = (float)svB[j]; aB1[j] = 0.f;
    }
    int i = 0;
    for (; i + 4 <= cnt; i += 4) {                 // 8 x 16B loads in flight
        int s0 = sED[ln][i],     s1 = sED[ln][i + 1];
        int s2 = sED[ln][i + 2], s3 = sED[ln][i + 3];
        f16x8 vA0 = gp[(size_t)s0 * 16 + c8];
        f16x8 vB0 = gp[(size_t)s0 * 16 + c8 + 8];
        f16x8 vA1 = gp[(size_t)s1 * 16 + c8];
        f16x8 vB1 = gp[(size_t)s1 * 16 + c8 + 8];
        f16x8 vA2 = gp[(size_t)s2 * 16 + c8];
        f16x8 vB2 = gp[(size_t)s2 * 16 + c8 + 8];
        f16x8 vA3 = gp[(size_t)s3 * 16 + c8];
        f16x8 vB3 = gp[(size_t)s3 * 16 + c8 + 8];
#pragma unroll
        for (int j = 0; j < 8; j++) {
            aA0[j] += (float)vA0[j] + (float)vA2[j];
            aA1[j] += (float)vA1[j] + (float)vA3[j];
            aB0[j] += (float)vB0[j] + (float)vB2[j];
            aB1[j] += (float)vB1[j] + (float)vB3[j];
        }
    }
    for (; i < cnt; i++) {
        int s = sED[ln][i];
        f16x8 vA = gp[(size_t)s * 16 + c8];
        f16x8 vB = gp[(size_t)s * 16 + c8 + 8];
#pragma unroll
        for (int j = 0; j < 8; j++) {
            aA0[j] += (float)vA[j];
            aB0[j] += (float)vB[j];
        }
    }
    for (int e = e0 + 64; e < e1; e++) {           // rare deg>64 overflow
        int s = ssrc[e];
        f16x8 vA = gp[(size_t)s * 16 + c8];
        f16x8 vB = gp[(size_t)s * 16 + c8 + 8];
#pragma unroll
        for (int j = 0; j < 8; j++) {
            aA0[j] += (float)vA[j];
            aB0[j] += (float)vB[j];
        }
    }

    {
        float dv = dinv[gr];
        short8 h8, l8;
#pragma unroll
        for (int j = 0; j < 8; j++) {
            float o = (aA0[j] + aA1[j]) * dv + bias[c8 * 8 + j];
            o = fmaxf(o, 0.f);                     // relu (both fused layers)
            short h, l;
            split_bf16(o, h, l);
            h8[j] = h; l8[j] = l;
        }
        int ao0 = ln * 64 + ((c8 ^ (ln & 7)) * 8); // K-tile 0, row ln, group c8
        *(short8*)&sAh[ao0] = h8;
        *(short8*)&sAl[ao0] = l8;
#pragma unroll
        for (int j = 0; j < 8; j++) {
            float o = (aB0[j] + aB1[j]) * dv + bias[(c8 + 8) * 8 + j];
            o = fmaxf(o, 0.f);
            short h, l;
            split_bf16(o, h, l);
            h8[j] = h; l8[j] = l;
        }
        int ao1 = BM * 64 + ao0;                   // K-tile 1
        *(short8*)&sAh[ao1] = h8;
        *(short8*)&sAl[ao1] = l8;
    }
    __syncthreads();                               // A ready; uB free for B

    // ---- phase B: gemm ----
    const int fr = lane & 15, fq = lane >> 4;
    const int lr = lane >> 3, lz = lane & 7;
    const int swz = (lz ^ lr) * 8;
    const int wr = w >> 1, wc = w & 1;
    floatx4 acc[NT] = {};

    if constexpr (BN == 128) {
        short* sB = (short*)uB;                    // one half: 128*64*2B = 16KB
#pragma unroll
        for (int kt = 0; kt < 2; kt++) {
            // stage H half
#pragma unroll
            for (int jj = 0; jj < 4; jj++) {
                int j = w * 4 + jj;
                size_t go = (size_t)(j * 8 + lr) * 128 + kt * 64 + swz;
                async16(&Bh[go], &sB[j * 512 + lane * 8]);
            }
            __syncthreads();
#pragma unroll
            for (int ks = 0; ks < 2; ks++) {
                int R = wr * 16 + fr;
                int ca = kt * (BM * 64) + R * 64 + (((ks * 4 + fq) ^ (R & 7)) * 8);
                short8 ah = *(const short8*)&sAh[ca];
                short8 al = *(const short8*)&sAl[ca];
#pragma unroll
                for (int nt = 0; nt < NT; nt++) {
                    int n = wc * (BN / 2) + nt * 16 + fr;
                    int cb = n * 64 + (((ks * 4 + fq) ^ (n & 7)) * 8);
                    short8 bh = *(const short8*)&sB[cb];
                    acc[nt] = __builtin_amdgcn_mfma_f32_16x16x32_bf16(ah, bh, acc[nt], 0, 0, 0);
                    acc[nt] = __builtin_amdgcn_mfma_f32_16x16x32_bf16(al, bh, acc[nt], 0, 0, 0);
                }
            }
            __syncthreads();
            // stage L half (same buffer)
#pragma unroll
            for (int jj = 0; jj < 4; jj++) {
                int j = w * 4 + jj;
                size_t go = (size_t)(j * 8 + lr) * 128 + kt * 64 + swz;
                async16(&Bl[go], &sB[j * 512 + lane * 8]);
            }
            __syncthreads();
#pragma unroll
            for (int ks = 0; ks < 2; ks++) {
                int R = wr * 16 + fr;
                int ca = kt * (BM * 64) + R * 64 + (((ks * 4 + fq) ^ (R & 7)) * 8);
                short8 ah = *(const short8*)&sAh[ca];
#pragma unroll
                for (int nt = 0; nt < NT; nt++) {
                    int n = wc * (BN / 2) + nt * 16 + fr;
                    int cb = n * 64 + (((ks * 4 + fq) ^ (n & 7)) * 8);
                    short8 bl = *(const short8*)&sB[cb];
                    acc[nt] = __builtin_amdgcn_mfma_f32_16x16x32_bf16(ah, bl, acc[nt], 0, 0, 0);
                }
            }
            __syncthreads();
        }
    } else {
        short* sBh_ = (short*)uB;                  // 64*64*2B = 8KB
        short* sBl_ = (short*)uB + 64 * 64;        // 8KB
#pragma unroll
        for (int kt = 0; kt < 2; kt++) {
#pragma unroll
            for (int jj = 0; jj < 2; jj++) {
                int j = w * 2 + jj;
                size_t go = (size_t)(j * 8 + lr) * 128 + kt * 64 + swz;
                async16(&Bh[go], &sBh_[j * 512 + lane * 8]);
                async16(&Bl[go], &sBl_[j * 512 + lane * 8]);
            }
            __syncthreads();
#pragma unroll
            for (int ks = 0; ks < 2; ks++) {
                int R = wr * 16 + fr;
                int ca = kt * (BM * 64) + R * 64 + (((ks * 4 + fq) ^ (R & 7)) * 8);
                short8 ah = *(const short8*)&sAh[ca];
                short8 al = *(const short8*)&sAl[ca];
#pragma unroll
                for (int nt = 0; nt < NT; nt++) {
                    int n = wc * (BN / 2) + nt * 16 + fr;
                    int cb = n * 64 + (((ks * 4 + fq) ^ (n & 7)) * 8);
                    short8 bh = *(const short8*)&sBh_[cb];
                    short8 bl = *(const short8*)&sBl_[cb];
                    acc[nt] = __builtin_amdgcn_mfma_f32_16x16x32_bf16(ah, bh, acc[nt], 0, 0, 0);
                    acc[nt] = __builtin_amdgcn_mfma_f32_16x16x32_bf16(ah, bl, acc[nt], 0, 0, 0);
                    acc[nt] = __builtin_amdgcn_mfma_f32_16x16x32_bf16(al, bh, acc[nt], 0, 0, 0);
                }
            }
            __syncthreads();
        }
    }

#pragma unroll
    for (int rr = 0; rr < 4; rr++) {
        int grow = row0 + wr * 16 + fq * 4 + rr;
        if (grow < NNODES) {
            float dv = dinv[grow];
#pragma unroll
            for (int nt = 0; nt < NT; nt++)
                gout[(size_t)grow * BN + wc * (BN / 2) + nt * 16 + fr] =
                    (_Float16)(acc[nt][rr] * dv);
        }
    }
}

// ------ Final aggregation (layer 2, F=64): dual-chunk gather, fp32 out ---

__global__ __launch_bounds__(256) void k_agg64(const _Float16* __restrict__ g,
                                               const int* __restrict__ ssrc,
                                               const int* __restrict__ rowptr,
                                               const float* __restrict__ dinv,
                                               const float* __restrict__ bias,
                                               float* __restrict__ outf) {
    constexpr int NPB = 64;
    __shared__ int sED[NPB][64];       // 16KB
    int t = threadIdx.x;
    int ln = t >> 2;                   // node (0..63)
    int c8 = t & 3;                    // chunk pair: c8 and c8+4 (of 8)
    int n = blockIdx.x * NPB + ln;
    bool valid = (n < NNODES);
    int nc = valid ? n : NNODES - 1;

    int e0 = rowptr[nc], e1 = rowptr[nc + 1];
    int deg = e1 - e0;
    int cnt = deg < 64 ? deg : 64;
    for (int i = c8; i < cnt; i += 4) sED[ln][i] = ssrc[e0 + i];
    __syncthreads();

    const f16x8* gp = (const f16x8*)g;
    f16x8 svA = gp[(size_t)nc * 8 + c8];          // self term
    f16x8 svB = gp[(size_t)nc * 8 + c8 + 4];
    float aA0[8], aA1[8], aB0[8], aB1[8];
#pragma unroll
    for (int j = 0; j < 8; j++) {
        aA0[j] = (float)svA[j]; aA1[j] = 0.f;
        aB0[j] = (float)svB[j]; aB1[j] = 0.f;
    }
    int i = 0;
    for (; i + 4 <= cnt; i += 4) {
        int s0 = sED[ln][i],     s1 = sED[ln][i + 1];
        int s2 = sED[ln][i + 2], s3 = sED[ln][i + 3];
        f16x8 vA0 = gp[(size_t)s0 * 8 + c8];
        f16x8 vB0 = gp[(size_t)s0 * 8 + c8 + 4];
        f16x8 vA1 = gp[(size_t)s1 * 8 + c8];
        f16x8 vB1 = gp[(size_t)s1 * 8 + c8 + 4];
        f16x8 vA2 = gp[(size_t)s2 * 8 + c8];
        f16x8 vB2 = gp[(size_t)s2 * 8 + c8 + 4];
        f16x8 vA3 = gp[(size_t)s3 * 8 + c8];
        f16x8 vB3 = gp[(size_t)s3 * 8 + c8 + 4];
#pragma unroll
        for (int j = 0; j < 8; j++) {
            aA0[j] += (float)vA0[j] + (float)vA2[j];
            aA1[j] += (float)vA1[j] + (float)vA3[j];
            aB0[j] += (float)vB0[j] + (float)vB2[j];
            aB1[j] += (float)vB1[j] + (float)vB3[j];
        }
    }
    for (; i < cnt; i++) {
        int s = sED[ln][i];
        f16x8 vA = gp[(size_t)s * 8 + c8];
        f16x8 vB = gp[(size_t)s * 8 + c8 + 4];
#pragma unroll
        for (int j = 0; j < 8; j++) {
            aA0[j] += (float)vA[j];
            aB0[j] += (float)vB[j];
        }
    }
    for (int e = e0 + 64; e < e1; e++) {
        int s = ssrc[e];
        f16x8 vA = gp[(size_t)s * 8 + c8];
        f16x8 vB = gp[(size_t)s * 8 + c8 + 4];
#pragma unroll
        for (int j = 0; j < 8; j++) {
            aA0[j] += (float)vA[j];
            aB0[j] += (float)vB[j];
        }
    }

    if (!valid) return;
    float dv = dinv[nc];
    float oA[8], oB[8];
#pragma unroll
    for (int j = 0; j < 8; j++) {
        oA[j] = (aA0[j] + aA1[j]) * dv + bias[c8 * 8 + j];
        oB[j] = (aB0[j] + aB1[j]) * dv + bias[(c8 + 4) * 8 + j];
    }
    *(float4*)&outf[(size_t)n * 64 + c8 * 8] =
        make_float4(oA[0], oA[1], oA[2], oA[3]);
    *(float4*)&outf[(size_t)n * 64 + c8 * 8 + 4] =
        make_float4(oA[4], oA[5], oA[6], oA[7]);
    *(float4*)&outf[(size_t)n * 64 + (c8 + 4) * 8] =
        make_float4(oB[0], oB[1], oB[2], oB[3]);
    *(float4*)&outf[(size_t)n * 64 + (c8 + 4) * 8 + 4] =
        make_float4(oB[4], oB[5], oB[6], oB[7]);
}

// ---------------- launch ----------------

static inline size_t align256(size_t x) { return (x + 255) & ~(size_t)255; }

extern "C" void kernel_launch(void* const* d_in, const int* in_sizes, int n_in,
                              void* d_out, int out_size, void* d_ws, size_t ws_size,
                              hipStream_t stream) {
    const float* x  = (const float*)d_in[0];
    const int*   ei = (const int*)d_in[1];
    const float* W0 = (const float*)d_in[2];
    const float* b0 = (const float*)d_in[3];
    const float* W1 = (const float*)d_in[4];
    const float* b1 = (const float*)d_in[5];
    const float* W2 = (const float*)d_in[6];
    const float* b2 = (const float*)d_in[7];
    float* out = (float*)d_out;

    const int* src = ei;
    const int* dst = ei + NEDGES;

    char* w = (char*)d_ws;
    size_t off = 0;
    float* dinv    = (float*)(w + off); off = align256(off + NNODES * 4);
    int* deg       = (int*)(w + off);   off = align256(off + NNODES * 4);
    int* rowptr    = (int*)(w + off);   off = align256(off + (NNODES + 1) * 4);
    int* hist2d    = (int*)(w + off);   off = align256(off + 256 * 256 * 4);
    unsigned* buck = (unsigned*)(w + off); off = align256(off + (size_t)NEDGES * 4);
    int* ssrc      = (int*)(w + off);   off = align256(off + (size_t)NEDGES * 4);
    short* W0h     = (short*)(w + off); off = align256(off + 256 * 128 * 2);
    short* W0l     = (short*)(w + off); off = align256(off + 256 * 128 * 2);
    short* W1h     = (short*)(w + off); off = align256(off + 128 * 128 * 2);
    short* W1l     = (short*)(w + off); off = align256(off + 128 * 128 * 2);
    short* W2h     = (short*)(w + off); off = align256(off + 128 * 64 * 2);
    short* W2l     = (short*)(w + off); off = align256(off + 128 * 64 * 2);
    _Float16* g16a = (_Float16*)(w + off); off = align256(off + (size_t)NNODES * 128 * 2);
    _Float16* g16b = (_Float16*)(w + off); off = align256(off + (size_t)NNODES * 128 * 2);
    _Float16* g16c = (_Float16*)(w + off); off = align256(off + (size_t)NNODES * 64 * 2);

    const int FB = (NNODES + 31) / 32;            // 1563 (fused, 32 rows/block)
    const int AB = (NNODES + 63) / 64;            // 782 (final agg, 64 nodes/block)

    // 0) zero fine-degree counters (graph-capturable async memset)
    hipMemsetAsync(deg, 0, NNODES * sizeof(int), stream);
    // 1) prep: weights + coarse histogram + deg atomics
    k_prep<<<PREP_TOT, 256, 0, stream>>>(W0, W0h, W0l, W1, W1h, W1l,
                                         W2, W2h, W2l, dst, hist2d, deg);
    // 2) FUSED: coarse scatter (blocks 0..255) || gemm0 (blocks 256..)
    k_p2g0<<<256 + G0_MB, 256, 0, stream>>>(src, dst, hist2d, buck,
                                            x, W0h, W0l, deg, g16a);
    // 3) finalize: rowptr/dinv/ssrc
    k_p3<<<256, 256, 0, stream>>>(buck, hist2d, rowptr, dinv, ssrc);

    // fused: agg0 (+b0, relu) -> gemm1 -> g16b
    k_fagg<128><<<FB, 256, 0, stream>>>(g16a, ssrc, rowptr, dinv, b0,
                                        W1h, W1l, g16b);
    // fused: agg1 (+b1, relu) -> gemm2 -> g16c
    k_fagg<64><<<FB, 256, 0, stream>>>(g16b, ssrc, rowptr, dinv, b1,
                                       W2h, W2l, g16c);
    // final: agg2 (+b2, no relu) -> fp32 out
    k_agg64<<<AB, 256, 0, stream>>>(g16c, ssrc, rowptr, dinv, b2, out);
    (void)in_sizes; (void)n_in; (void)out_size; (void)ws_size;
}

// Round 7
// 230.888 us; speedup vs baseline: 1.1274x; 1.1274x over previous
//
#include <hip/hip_runtime.h>

#define NNODES 50000
#define NEDGES 800000
#define CHUNK 3125          // edges per CSR block (256 blocks * 3125 = 800000)

typedef __attribute__((ext_vector_type(8))) short short8;
typedef __attribute__((ext_vector_type(4))) float floatx4;
typedef __attribute__((ext_vector_type(8))) _Float16 f16x8;

// async global->LDS, 16B per lane (global_load_lds_dwordx4).
// LDS dest MUST be wave-uniform base + lane*16.
__device__ __forceinline__ void async16(const void* g, void* l) {
    __builtin_amdgcn_global_load_lds(
        (const __attribute__((address_space(1))) unsigned int*)g,
        (__attribute__((address_space(3))) unsigned int*)l, 16, 0, 0);
}

__device__ __forceinline__ void split_bf16(float v, short& hi, short& lo) {
    unsigned u = __float_as_uint(v);
    unsigned hu = u & 0xffff0000u;
    hi = (short)(hu >> 16);
    float r = v - __uint_as_float(hu);
    lo = (short)(__float_as_uint(r) >> 16);
}

// ------ prep: weight transpose/split + coarse histogram (R0) -------------

#define PREP_WBLK 224
#define PREP_TOT  (PREP_WBLK + 256)

__global__ __launch_bounds__(256) void k_prep(
    const float* __restrict__ W0, short* __restrict__ W0h, short* __restrict__ W0l,
    const float* __restrict__ W1, short* __restrict__ W1h, short* __restrict__ W1l,
    const float* __restrict__ W2, short* __restrict__ W2h, short* __restrict__ W2l,
    const int* __restrict__ dst, int* __restrict__ hist2d) {
    int b = blockIdx.x, t = threadIdx.x;
    if (b < PREP_WBLK) {
        int id = b * 256 + t;
        const float* W; short *Wh, *Wl; int K, F;
        if (id < 32768) { W = W0; Wh = W0h; Wl = W0l; K = 256; F = 128; }
        else if (id < 49152) { id -= 32768; W = W1; Wh = W1h; Wl = W1l; K = 128; F = 128; }
        else if (id < 57344) { id -= 49152; W = W2; Wh = W2h; Wl = W2l; K = 128; F = 64; }
        else return;
        int f = id / K, k = id - f * K;
        short h, l;
        split_bf16(W[(size_t)k * F + f], h, l);
        Wh[id] = h;
        Wl[id] = l;
    } else {
        // per-block coarse histogram of dst>>8 (no global atomics)
        __shared__ int h[256];
        int bb = b - PREP_WBLK;
        h[t] = 0;
        __syncthreads();
        int e0 = bb * CHUNK;
#pragma unroll
        for (int k = 0; k < 13; k++) {
            int o = k * 256 + t;
            if (o < CHUNK) atomicAdd(&h[dst[e0 + o] >> 8], 1);
        }
        __syncthreads();
        hist2d[bb * 256 + t] = h[t];
    }
}

// ------ k_scan (R7, 1 block): precompute the 2D prefix sums ONCE ---------
// Replaces p2's and p3's per-block 256KB hist2d re-scans (128MB of reads
// across 512 blocks) with one pass: scanned[bb][t] = sum_{b'<bb} hist[b'][t]
// (coalesced across t), gbase[t] = global base of coarse bin t,
// gbase[256] = NEDGES.

__global__ __launch_bounds__(256) void k_scan(const int* __restrict__ hist2d,
                                              int* __restrict__ scanned,
                                              int* __restrict__ gbase) {
    int t = threadIdx.x;
    int run = 0;
    for (int bb = 0; bb < 256; bb++) {
        int v = hist2d[bb * 256 + t];
        scanned[bb * 256 + t] = run;
        run += v;
    }
    __shared__ int ex[256];
    ex[t] = run;                       // total of coarse bin t
    __syncthreads();
    for (int o = 1; o < 256; o <<= 1) {
        int xx = (t >= o) ? ex[t - o] : 0;
        __syncthreads();
        ex[t] += xx;
        __syncthreads();
    }
    gbase[t] = ex[t] - run;            // exclusive over t
    if (t == 255) gbase[256] = ex[t];  // == NEDGES
}

// P2 (R7): deterministic coarse scatter; cursor bases read precomputed.
__global__ __launch_bounds__(256) void k_p2(const int* __restrict__ src,
                                            const int* __restrict__ dst,
                                            const int* __restrict__ scanned,
                                            const int* __restrict__ gbase,
                                            unsigned* __restrict__ buck) {
    __shared__ int cur[256];
    int t = threadIdx.x, b = blockIdx.x;
    cur[t] = gbase[t] + scanned[b * 256 + t];
    __syncthreads();
    int e0 = b * CHUNK;
#pragma unroll
    for (int k = 0; k < 13; k++) {
        int o = k * 256 + t;
        if (o < CHUNK) {
            int s = src[e0 + o], d = dst[e0 + o];
            int p = atomicAdd(&cur[d >> 8], 1);   // LDS atomic only
            buck[p] = (unsigned)s | ((unsigned)(d & 255) << 16);
        }
    }
}

// P3 (R7): finalize coarse bin b -> rowptr/dinv/ssrc; bases precomputed.
__global__ __launch_bounds__(256) void k_p3(const unsigned* __restrict__ buck,
                                            const int* __restrict__ gbase,
                                            int* __restrict__ rowptr,
                                            float* __restrict__ dinv,
                                            int* __restrict__ ssrc) {
    __shared__ int ex[256], cur[256], h[256];
    int t = threadIdx.x, b = blockIdx.x;
    int s0 = gbase[b];
    int S = gbase[b + 1] - s0;
    h[t] = 0;
    __syncthreads();
    for (int i = t; i < S; i += 256)
        atomicAdd(&h[(buck[s0 + i] >> 16) & 255], 1);
    __syncthreads();
    int v = h[t];
    ex[t] = v;
    __syncthreads();
    for (int o = 1; o < 256; o <<= 1) {
        int xx = (t >= o) ? ex[t - o] : 0;
        __syncthreads();
        ex[t] += xx;
        __syncthreads();
    }
    int excl = ex[t] - v;
    int n = b * 256 + t;
    if (n < NNODES) {
        rowptr[n] = s0 + excl;
        dinv[n] = rsqrtf((float)v + 1.0f);
    }
    if (b == 0 && t == 0) rowptr[NNODES] = NEDGES;
    cur[t] = excl;
    __syncthreads();
    for (int i = t; i < S; i += 256) {
        unsigned pk = buck[s0 + i];
        int dl = (pk >> 16) & 255;
        int p = atomicAdd(&cur[dl], 1);
        ssrc[s0 + p] = (int)(pk & 0xFFFFu);
    }
}

// ------ gemm0: g16 = fp16((x @ W0) * dinv[row]) (R0, proven) -------------

__global__ __launch_bounds__(256) void k_gemm0(
    const float* __restrict__ x, const short* __restrict__ Bh,
    const short* __restrict__ Bl, const float* __restrict__ dinv,
    _Float16* __restrict__ g16) {
    __shared__ __align__(16) short sAh[64 * 64], sAl[64 * 64];
    __shared__ __align__(16) short sBh[128 * 64], sBl[128 * 64];
    const int t = threadIdx.x, lane = t & 63, w = t >> 6;
    const int row0 = blockIdx.x * 64;
    const int lr = lane >> 3, lz = lane & 7;
    const int swz = (lz ^ lr) * 8;
    const int fr = lane & 15, fq = lane >> 4;
    floatx4 acc[8] = {};
    const int ar = t >> 2, ac = t & 3;
    int garow = row0 + ar;
    if (garow >= NNODES) garow = NNODES - 1;
    const float* xrow = x + (size_t)garow * 256 + ac * 16;

    for (int k0 = 0; k0 < 256; k0 += 64) {
        const float4* xp = (const float4*)(xrow + k0);
        float4 f0 = xp[0], f1 = xp[1], f2 = xp[2], f3 = xp[3];
        float va[16] = {f0.x, f0.y, f0.z, f0.w, f1.x, f1.y, f1.z, f1.w,
                        f2.x, f2.y, f2.z, f2.w, f3.x, f3.y, f3.z, f3.w};
        short8 h0, h1, l0, l1;
#pragma unroll
        for (int j = 0; j < 8; j++) {
            short h, l;
            split_bf16(va[j], h, l);     h0[j] = h; l0[j] = l;
            split_bf16(va[8 + j], h, l); h1[j] = h; l1[j] = l;
        }
        int c0 = ac * 2;
        *(short8*)&sAh[ar * 64 + ((c0 ^ (ar & 7)) * 8)] = h0;
        *(short8*)&sAh[ar * 64 + (((c0 + 1) ^ (ar & 7)) * 8)] = h1;
        *(short8*)&sAl[ar * 64 + ((c0 ^ (ar & 7)) * 8)] = l0;
        *(short8*)&sAl[ar * 64 + (((c0 + 1) ^ (ar & 7)) * 8)] = l1;
#pragma unroll
        for (int jj = 0; jj < 4; jj++) {
            int j = w * 4 + jj;
            size_t go = (size_t)(j * 8 + lr) * 256 + k0 + swz;
            async16(&Bh[go], &sBh[j * 512 + lane * 8]);
            async16(&Bl[go], &sBl[j * 512 + lane * 8]);
        }
        __syncthreads();
#pragma unroll
        for (int ks = 0; ks < 2; ks++) {
            int R = w * 16 + fr;
            int ca = ((ks * 4 + fq) ^ (R & 7)) * 8;
            short8 ah = *(const short8*)&sAh[R * 64 + ca];
            short8 al = *(const short8*)&sAl[R * 64 + ca];
#pragma unroll
            for (int nt = 0; nt < 8; nt++) {
                int n = nt * 16 + fr;
                int cb = ((ks * 4 + fq) ^ (n & 7)) * 8;
                short8 bh = *(const short8*)&sBh[n * 64 + cb];
                short8 bl = *(const short8*)&sBl[n * 64 + cb];
                acc[nt] = __builtin_amdgcn_mfma_f32_16x16x32_bf16(ah, bh, acc[nt], 0, 0, 0);
                acc[nt] = __builtin_amdgcn_mfma_f32_16x16x32_bf16(ah, bl, acc[nt], 0, 0, 0);
                acc[nt] = __builtin_amdgcn_mfma_f32_16x16x32_bf16(al, bh, acc[nt], 0, 0, 0);
            }
        }
        __syncthreads();
    }
#pragma unroll
    for (int rr = 0; rr < 4; rr++) {
        int gw = row0 + w * 16 + fq * 4 + rr;
        if (gw < NNODES) {
            float dv = dinv[gw];
#pragma unroll
            for (int nt = 0; nt < 8; nt++)
                g16[(size_t)gw * 128 + nt * 16 + fr] =
                    (_Float16)(acc[nt][rr] * dv);
        }
    }
}

// ------ FUSED agg(layer L) + gemm(layer L+1) (R5, proven) ----------------
// Phase A: single pass, 8 threads/row x 32 rows, 2 chunks/thread ->
// 8 gather loads in flight with the 4-edge unroll. LDS 32KB.

template <int BN>
__global__ __launch_bounds__(256) void k_fagg(
    const _Float16* __restrict__ gin,
    const int* __restrict__ ssrc,
    const int* __restrict__ rowptr,
    const float* __restrict__ dinv,
    const float* __restrict__ bias,
    const short* __restrict__ Bh, const short* __restrict__ Bl,
    _Float16* __restrict__ gout) {
    constexpr int BM = 32;
    constexpr int NT = BN / 32;          // col tiles per wave (4 or 2)
    __shared__ __align__(16) short sAh[2 * BM * 64], sAl[2 * BM * 64]; // 8+8 KB
    __shared__ __align__(16) char uB[16384];                          // 16 KB union

    const int t = threadIdx.x, lane = t & 63, w = t >> 6;
    const int row0 = blockIdx.x * BM;

    // ---- phase A: aggregate (single pass; sED aliases uB) ----
    int (*sED)[64] = (int(*)[64])uB;    // 32 x 64 ints = 8KB
    const int ln = t >> 3;      // row (0..31)
    const int c8 = t & 7;       // chunk pair: handles c8 and c8+8
    const f16x8* gp = (const f16x8*)gin;

    int gr = row0 + ln;
    if (gr >= NNODES) gr = NNODES - 1;
    int e0 = rowptr[gr], e1 = rowptr[gr + 1];
    int deg = e1 - e0;
    int cnt = deg < 64 ? deg : 64;
    for (int i = c8; i < cnt; i += 8) sED[ln][i] = ssrc[e0 + i];
    __syncthreads();

    f16x8 svA = gp[(size_t)gr * 16 + c8];          // self term
    f16x8 svB = gp[(size_t)gr * 16 + c8 + 8];
    float aA0[8], aA1[8], aB0[8], aB1[8];
#pragma unroll
    for (int j = 0; j < 8; j++) {
        aA0[j] = (float)svA[j]; aA1[j] = 0.f;
        aB0[j] = (float)svB[j]; aB1[j] = 0.f;
    }
    int i = 0;
    for (; i + 4 <= cnt; i += 4) {                 // 8 x 16B loads in flight
        int s0 = sED[ln][i],     s1 = sED[ln][i + 1];
        int s2 = sED[ln][i + 2], s3 = sED[ln][i + 3];
        f16x8 vA0 = gp[(size_t)s0 * 16 + c8];
        f16x8 vB0 = gp[(size_t)s0 * 16 + c8 + 8];
        f16x8 vA1 = gp[(size_t)s1 * 16 + c8];
        f16x8 vB1 = gp[(size_t)s1 * 16 + c8 + 8];
        f16x8 vA2 = gp[(size_t)s2 * 16 + c8];
        f16x8 vB2 = gp[(size_t)s2 * 16 + c8 + 8];
        f16x8 vA3 = gp[(size_t)s3 * 16 + c8];
        f16x8 vB3 = gp[(size_t)s3 * 16 + c8 + 8];
#pragma unroll
        for (int j = 0; j < 8; j++) {
            aA0[j] += (float)vA0[j] + (float)vA2[j];
            aA1[j] += (float)vA1[j] + (float)vA3[j];
            aB0[j] += (float)vB0[j] + (float)vB2[j];
            aB1[j] += (float)vB1[j] + (float)vB3[j];
        }
    }
    for (; i < cnt; i++) {
        int s = sED[ln][i];
        f16x8 vA = gp[(size_t)s * 16 + c8];
        f16x8 vB = gp[(size_t)s * 16 + c8 + 8];
#pragma unroll
        for (int j = 0; j < 8; j++) {
            aA0[j] += (float)vA[j];
            aB0[j] += (float)vB[j];
        }
    }
    for (int e = e0 + 64; e < e1; e++) {           // rare deg>64 overflow
        int s = ssrc[e];
        f16x8 vA = gp[(size_t)s * 16 + c8];
        f16x8 vB = gp[(size_t)s * 16 + c8 + 8];
#pragma unroll
        for (int j = 0; j < 8; j++) {
            aA0[j] += (float)vA[j];
            aB0[j] += (float)vB[j];
        }
    }

    {
        float dv = dinv[gr];
        short8 h8, l8;
#pragma unroll
        for (int j = 0; j < 8; j++) {
            float o = (aA0[j] + aA1[j]) * dv + bias[c8 * 8 + j];
            o = fmaxf(o, 0.f);                     // relu (both fused layers)
            short h, l;
            split_bf16(o, h, l);
            h8[j] = h; l8[j] = l;
        }
        int ao0 = ln * 64 + ((c8 ^ (ln & 7)) * 8); // K-tile 0, row ln, group c8
        *(short8*)&sAh[ao0] = h8;
        *(short8*)&sAl[ao0] = l8;
#pragma unroll
        for (int j = 0; j < 8; j++) {
            float o = (aB0[j] + aB1[j]) * dv + bias[(c8 + 8) * 8 + j];
            o = fmaxf(o, 0.f);
            short h, l;
            split_bf16(o, h, l);
            h8[j] = h; l8[j] = l;
        }
        int ao1 = BM * 64 + ao0;                   // K-tile 1
        *(short8*)&sAh[ao1] = h8;
        *(short8*)&sAl[ao1] = l8;
    }
    __syncthreads();                               // A ready; uB free for B

    // ---- phase B: gemm ----
    const int fr = lane & 15, fq = lane >> 4;
    const int lr = lane >> 3, lz = lane & 7;
    const int swz = (lz ^ lr) * 8;
    const int wr = w >> 1, wc = w & 1;
    floatx4 acc[NT] = {};

    if constexpr (BN == 128) {
        short* sB = (short*)uB;                    // one half: 128*64*2B = 16KB
#pragma unroll
        for (int kt = 0; kt < 2; kt++) {
            // stage H half
#pragma unroll
            for (int jj = 0; jj < 4; jj++) {
                int j = w * 4 + jj;
                size_t go = (size_t)(j * 8 + lr) * 128 + kt * 64 + swz;
                async16(&Bh[go], &sB[j * 512 + lane * 8]);
            }
            __syncthreads();
#pragma unroll
            for (int ks = 0; ks < 2; ks++) {
                int R = wr * 16 + fr;
                int ca = kt * (BM * 64) + R * 64 + (((ks * 4 + fq) ^ (R & 7)) * 8);
                short8 ah = *(const short8*)&sAh[ca];
                short8 al = *(const short8*)&sAl[ca];
#pragma unroll
                for (int nt = 0; nt < NT; nt++) {
                    int n = wc * (BN / 2) + nt * 16 + fr;
                    int cb = n * 64 + (((ks * 4 + fq) ^ (n & 7)) * 8);
                    short8 bh = *(const short8*)&sB[cb];
                    acc[nt] = __builtin_amdgcn_mfma_f32_16x16x32_bf16(ah, bh, acc[nt], 0, 0, 0);
                    acc[nt] = __builtin_amdgcn_mfma_f32_16x16x32_bf16(al, bh, acc[nt], 0, 0, 0);
                }
            }
            __syncthreads();
            // stage L half (same buffer)
#pragma unroll
            for (int jj = 0; jj < 4; jj++) {
                int j = w * 4 + jj;
                size_t go = (size_t)(j * 8 + lr) * 128 + kt * 64 + swz;
                async16(&Bl[go], &sB[j * 512 + lane * 8]);
            }
            __syncthreads();
#pragma unroll
            for (int ks = 0; ks < 2; ks++) {
                int R = wr * 16 + fr;
                int ca = kt * (BM * 64) + R * 64 + (((ks * 4 + fq) ^ (R & 7)) * 8);
                short8 ah = *(const short8*)&sAh[ca];
#pragma unroll
                for (int nt = 0; nt < NT; nt++) {
                    int n = wc * (BN / 2) + nt * 16 + fr;
                    int cb = n * 64 + (((ks * 4 + fq) ^ (n & 7)) * 8);
                    short8 bl = *(const short8*)&sB[cb];
                    acc[nt] = __builtin_amdgcn_mfma_f32_16x16x32_bf16(ah, bl, acc[nt], 0, 0, 0);
                }
            }
            __syncthreads();
        }
    } else {
        short* sBh_ = (short*)uB;                  // 64*64*2B = 8KB
        short* sBl_ = (short*)uB + 64 * 64;        // 8KB
#pragma unroll
        for (int kt = 0; kt < 2; kt++) {
#pragma unroll
            for (int jj = 0; jj < 2; jj++) {
                int j = w * 2 + jj;
                size_t go = (size_t)(j * 8 + lr) * 128 + kt * 64 + swz;
                async16(&Bh[go], &sBh_[j * 512 + lane * 8]);
                async16(&Bl[go], &sBl_[j * 512 + lane * 8]);
            }
            __syncthreads();
#pragma unroll
            for (int ks = 0; ks < 2; ks++) {
                int R = wr * 16 + fr;
                int ca = kt * (BM * 64) + R * 64 + (((ks * 4 + fq) ^ (R & 7)) * 8);
                short8 ah = *(const short8*)&sAh[ca];
                short8 al = *(const short8*)&sAl[ca];
#pragma unroll
                for (int nt = 0; nt < NT; nt++) {
                    int n = wc * (BN / 2) + nt * 16 + fr;
                    int cb = n * 64 + (((ks * 4 + fq) ^ (n & 7)) * 8);
                    short8 bh = *(const short8*)&sBh_[cb];
                    short8 bl = *(const short8*)&sBl_[cb];
                    acc[nt] = __builtin_amdgcn_mfma_f32_16x16x32_bf16(ah, bh, acc[nt], 0, 0, 0);
                    acc[nt] = __builtin_amdgcn_mfma_f32_16x16x32_bf16(ah, bl, acc[nt], 0, 0, 0);
                    acc[nt] = __builtin_amdgcn_mfma_f32_16x16x32_bf16(al, bh, acc[nt], 0, 0, 0);
                }
            }
            __syncthreads();
        }
    }

#pragma unroll
    for (int rr = 0; rr < 4; rr++) {
        int grow = row0 + wr * 16 + fq * 4 + rr;
        if (grow < NNODES) {
            float dv = dinv[grow];
#pragma unroll
            for (int nt = 0; nt < NT; nt++)
                gout[(size_t)grow * BN + wc * (BN / 2) + nt * 16 + fr] =
                    (_Float16)(acc[nt][rr] * dv);
        }
    }
}

// ------ Final aggregation (layer 2, F=64): dual-chunk gather, fp32 out ---

__global__ __launch_bounds__(256) void k_agg64(const _Float16* __restrict__ g,
                                               const int* __restrict__ ssrc,
                                               const int* __restrict__ rowptr,
                                               const float* __restrict__ dinv,
                                               const float* __restrict__ bias,
                                               float* __restrict__ outf) {
    constexpr int NPB = 64;
    __shared__ int sED[NPB][64];       // 16KB
    int t = threadIdx.x;
    int ln = t >> 2;                   // node (0..63)
    int c8 = t & 3;                    // chunk pair: c8 and c8+4 (of 8)
    int n = blockIdx.x * NPB + ln;
    bool valid = (n < NNODES);
    int nc = valid ? n : NNODES - 1;

    int e0 = rowptr[nc], e1 = rowptr[nc + 1];
    int deg = e1 - e0;
    int cnt = deg < 64 ? deg : 64;
    for (int i = c8; i < cnt; i += 4) sED[ln][i] = ssrc[e0 + i];
    __syncthreads();

    const f16x8* gp = (const f16x8*)g;
    f16x8 svA = gp[(size_t)nc * 8 + c8];          // self term
    f16x8 svB = gp[(size_t)nc * 8 + c8 + 4];
    float aA0[8], aA1[8], aB0[8], aB1[8];
#pragma unroll
    for (int j = 0; j < 8; j++) {
        aA0[j] = (float)svA[j]; aA1[j] = 0.f;
        aB0[j] = (float)svB[j]; aB1[j] = 0.f;
    }
    int i = 0;
    for (; i + 4 <= cnt; i += 4) {
        int s0 = sED[ln][i],     s1 = sED[ln][i + 1];
        int s2 = sED[ln][i + 2], s3 = sED[ln][i + 3];
        f16x8 vA0 = gp[(size_t)s0 * 8 + c8];
        f16x8 vB0 = gp[(size_t)s0 * 8 + c8 + 4];
        f16x8 vA1 = gp[(size_t)s1 * 8 + c8];
        f16x8 vB1 = gp[(size_t)s1 * 8 + c8 + 4];
        f16x8 vA2 = gp[(size_t)s2 * 8 + c8];
        f16x8 vB2 = gp[(size_t)s2 * 8 + c8 + 4];
        f16x8 vA3 = gp[(size_t)s3 * 8 + c8];
        f16x8 vB3 = gp[(size_t)s3 * 8 + c8 + 4];
#pragma unroll
        for (int j = 0; j < 8; j++) {
            aA0[j] += (float)vA0[j] + (float)vA2[j];
            aA1[j] += (float)vA1[j] + (float)vA3[j];
            aB0[j] += (float)vB0[j] + (float)vB2[j];
            aB1[j] += (float)vB1[j] + (float)vB3[j];
        }
    }
    for (; i < cnt; i++) {
        int s = sED[ln][i];
        f16x8 vA = gp[(size_t)s * 8 + c8];
        f16x8 vB = gp[(size_t)s * 8 + c8 + 4];
#pragma unroll
        for (int j = 0; j < 8; j++) {
            aA0[j] += (float)vA[j];
            aB0[j] += (float)vB[j];
        }
    }
    for (int e = e0 + 64; e < e1; e++) {
        int s = ssrc[e];
        f16x8 vA = gp[(size_t)s * 8 + c8];
        f16x8 vB = gp[(size_t)s * 8 + c8 + 4];
#pragma unroll
        for (int j = 0; j < 8; j++) {
            aA0[j] += (float)vA[j];
            aB0[j] += (float)vB[j];
        }
    }

    if (!valid) return;
    float dv = dinv[nc];
    float oA[8], oB[8];
#pragma unroll
    for (int j = 0; j < 8; j++) {
        oA[j] = (aA0[j] + aA1[j]) * dv + bias[c8 * 8 + j];
        oB[j] = (aB0[j] + aB1[j]) * dv + bias[(c8 + 4) * 8 + j];
    }
    *(float4*)&outf[(size_t)n * 64 + c8 * 8] =
        make_float4(oA[0], oA[1], oA[2], oA[3]);
    *(float4*)&outf[(size_t)n * 64 + c8 * 8 + 4] =
        make_float4(oA[4], oA[5], oA[6], oA[7]);
    *(float4*)&outf[(size_t)n * 64 + (c8 + 4) * 8] =
        make_float4(oB[0], oB[1], oB[2], oB[3]);
    *(float4*)&outf[(size_t)n * 64 + (c8 + 4) * 8 + 4] =
        make_float4(oB[4], oB[5], oB[6], oB[7]);
}

// ---------------- launch ----------------

static inline size_t align256(size_t x) { return (x + 255) & ~(size_t)255; }

extern "C" void kernel_launch(void* const* d_in, const int* in_sizes, int n_in,
                              void* d_out, int out_size, void* d_ws, size_t ws_size,
                              hipStream_t stream) {
    const float* x  = (const float*)d_in[0];
    const int*   ei = (const int*)d_in[1];
    const float* W0 = (const float*)d_in[2];
    const float* b0 = (const float*)d_in[3];
    const float* W1 = (const float*)d_in[4];
    const float* b1 = (const float*)d_in[5];
    const float* W2 = (const float*)d_in[6];
    const float* b2 = (const float*)d_in[7];
    float* out = (float*)d_out;

    const int* src = ei;
    const int* dst = ei + NEDGES;

    char* w = (char*)d_ws;
    size_t off = 0;
    float* dinv    = (float*)(w + off); off = align256(off + NNODES * 4);
    int* rowptr    = (int*)(w + off);   off = align256(off + (NNODES + 1) * 4);
    int* hist2d    = (int*)(w + off);   off = align256(off + 256 * 256 * 4);
    int* scanned   = (int*)(w + off);   off = align256(off + 256 * 256 * 4);
    int* gbase     = (int*)(w + off);   off = align256(off + 257 * 4);
    unsigned* buck = (unsigned*)(w + off); off = align256(off + (size_t)NEDGES * 4);
    int* ssrc      = (int*)(w + off);   off = align256(off + (size_t)NEDGES * 4);
    short* W0h     = (short*)(w + off); off = align256(off + 256 * 128 * 2);
    short* W0l     = (short*)(w + off); off = align256(off + 256 * 128 * 2);
    short* W1h     = (short*)(w + off); off = align256(off + 128 * 128 * 2);
    short* W1l     = (short*)(w + off); off = align256(off + 128 * 128 * 2);
    short* W2h     = (short*)(w + off); off = align256(off + 128 * 64 * 2);
    short* W2l     = (short*)(w + off); off = align256(off + 128 * 64 * 2);
    _Float16* g16a = (_Float16*)(w + off); off = align256(off + (size_t)NNODES * 128 * 2);
    _Float16* g16b = (_Float16*)(w + off); off = align256(off + (size_t)NNODES * 128 * 2);
    _Float16* g16c = (_Float16*)(w + off); off = align256(off + (size_t)NNODES * 64 * 2);

    const int MB = (NNODES + 63) / 64;            // 782
    const int FB = (NNODES + 31) / 32;            // 1563 (fused, 32 rows/block)
    const int AB = (NNODES + 63) / 64;            // 782 (final agg, 64 nodes/block)

    // 1) prep: weights + coarse histogram
    k_prep<<<PREP_TOT, 256, 0, stream>>>(W0, W0h, W0l, W1, W1h, W1l,
                                         W2, W2h, W2l, dst, hist2d);
    // 1b) one-shot 2D scan (replaces 128MB of per-block re-scans in p2/p3)
    k_scan<<<1, 256, 0, stream>>>(hist2d, scanned, gbase);
    // 2) coarse scatter
    k_p2<<<256, 256, 0, stream>>>(src, dst, scanned, gbase, buck);
    // 3) finalize: rowptr/dinv/ssrc
    k_p3<<<256, 256, 0, stream>>>(buck, gbase, rowptr, dinv, ssrc);

    // layer 0 gemm (direct x)
    k_gemm0<<<MB, 256, 0, stream>>>(x, W0h, W0l, dinv, g16a);
    // fused: agg0 (+b0, relu) -> gemm1 -> g16b
    k_fagg<128><<<FB, 256, 0, stream>>>(g16a, ssrc, rowptr, dinv, b0,
                                        W1h, W1l, g16b);
    // fused: agg1 (+b1, relu) -> gemm2 -> g16c
    k_fagg<64><<<FB, 256, 0, stream>>>(g16b, ssrc, rowptr, dinv, b1,
                                       W2h, W2l, g16c);
    // final: agg2 (+b2, no relu) -> fp32 out
    k_agg64<<<AB, 256, 0, stream>>>(g16c, ssrc, rowptr, dinv, b2, out);
    (void)in_sizes; (void)n_in; (void)out_size; (void)ws_size;
}